// Round 2
// baseline (33543.433 us; speedup 1.0000x reference)
//
#include <hip/hip_runtime.h>
#include <hip/hip_bf16.h>

typedef __hip_bfloat16 bf16;

#define B_ 64
#define T_ 250
#define D_ 768
#define H_ 12
#define DH_ 64
#define F_ 32
#define L_ 12
#define BT_ (B_*T_)   // 16000

__device__ __forceinline__ float toF(float v) { return v; }
__device__ __forceinline__ float toF(bf16 v) { return __bfloat162float(v); }
__device__ __forceinline__ void storeF(float* p, float v) { *p = v; }
__device__ __forceinline__ void storeF(bf16* p, float v) { *p = __float2bfloat16(v); }

// ---------------- lengths (mask dtype autodetect: int32 / float32 / bool8) ----------------
__global__ void lengths_kernel(const unsigned char* __restrict__ mask, int* __restrict__ lengths) {
    __shared__ int not_i32, not_f32;
    const unsigned int* w = (const unsigned int*)mask;
    int tid = threadIdx.x;
    if (tid == 0) { not_i32 = 0; not_f32 = 0; }
    __syncthreads();
    int li = 0, lf = 0;
    for (int i = tid; i < 4000; i += 256) {   // first 4000 words is safe for all 3 dtypes
        unsigned int v = w[i];
        if (v > 1u) li = 1;
        if (v != 0u && v != 0x3F800000u) lf = 1;
    }
    if (li) not_i32 = 1;
    if (lf) not_f32 = 1;
    __syncthreads();
    int mode = (!not_i32) ? 0 : ((!not_f32) ? 1 : 2);
    if (tid < B_) {
        int cnt = 0;
        if (mode == 0) {
            const int* r = (const int*)mask + tid * T_;
            for (int t = 0; t < T_; ++t) cnt += (r[t] != 0);
        } else if (mode == 1) {
            const unsigned int* r = w + tid * T_;
            for (int t = 0; t < T_; ++t) cnt += (r[t] != 0);
        } else {
            const unsigned char* r = mask + tid * T_;
            for (int t = 0; t < T_; ++t) cnt += (r[t] != 0);
        }
        lengths[tid] = cnt;
    }
}

// ---------------- embedding ----------------
__global__ void embed_kernel(const int* __restrict__ batch, const float* __restrict__ tok,
                             const float* __restrict__ pos, float* __restrict__ x) {
    int bt = blockIdx.x;
    int t = bt % T_;
    int tok_id = batch[bt];
    const float* tr = tok + (size_t)tok_id * D_;
    const float* pr = pos + (size_t)t * D_;
    float* xr = x + (size_t)bt * D_;
    for (int d = threadIdx.x; d < D_; d += 256)
        xr[d] = tr[d] + pr[d];
}

// ---------------- SGEMM: C[16000,768] = A[16000,768] @ W[768,768] + bias, optional exact GELU ----------------
#define BM 64
#define BN 64
#define BK 16
template<typename AT, typename CT>
__global__ __launch_bounds__(256) void sgemm_bias(
    const AT* __restrict__ A, const float* __restrict__ W,
    const float* __restrict__ bias, CT* __restrict__ C, int act)
{
    __shared__ float As[BK][BM + 1];
    __shared__ float Bs[BK][BN + 1];
    const int K = D_, N = D_;
    int tid = threadIdx.x;
    int row0 = blockIdx.y * BM, col0 = blockIdx.x * BN;
    int tx = tid & 15, ty = tid >> 4;
    float acc[4][4] = {};
    for (int k0 = 0; k0 < K; k0 += BK) {
#pragma unroll
        for (int i = 0; i < 4; ++i) {
            int flat = tid + i * 256;
            int m = flat >> 4, kk = flat & 15;
            As[kk][m] = toF(A[(size_t)(row0 + m) * K + k0 + kk]);
        }
#pragma unroll
        for (int i = 0; i < 4; ++i) {
            int flat = tid + i * 256;
            int kk = flat >> 6, n = flat & 63;
            Bs[kk][n] = W[(size_t)(k0 + kk) * N + col0 + n];
        }
        __syncthreads();
#pragma unroll
        for (int kk = 0; kk < BK; ++kk) {
            float a[4], b[4];
#pragma unroll
            for (int i = 0; i < 4; ++i) a[i] = As[kk][ty * 4 + i];
#pragma unroll
            for (int j = 0; j < 4; ++j) b[j] = Bs[kk][tx * 4 + j];
#pragma unroll
            for (int i = 0; i < 4; ++i)
#pragma unroll
                for (int j = 0; j < 4; ++j)
                    acc[i][j] += a[i] * b[j];
        }
        __syncthreads();
    }
#pragma unroll
    for (int j = 0; j < 4; ++j) {
        float bj = bias[col0 + tx * 4 + j];
#pragma unroll
        for (int i = 0; i < 4; ++i) {
            float v = acc[i][j] + bj;
            if (act == 1) v = 0.5f * v * (1.0f + erff(v * 0.70710678118654752f));
            storeF(&C[(size_t)(row0 + ty * 4 + i) * N + col0 + tx * 4 + j], v);
        }
    }
}

// ---------------- feature map: out[bt,h,f] = relu(sum_dh q[bt,h*64+dh] * omega[dh,f]) ----------------
__global__ void feat_kernel(const bf16* __restrict__ qk, const float* __restrict__ omega,
                            float* __restrict__ out, const int* __restrict__ lengths, int masked) {
    int o = blockIdx.x * 256 + threadIdx.x;   // (bt, h, f)
    if (o >= BT_ * H_ * F_) return;
    int f = o & (F_ - 1);
    int h = (o >> 5) % H_;
    int bt = o / (H_ * F_);
    const bf16* qrow = qk + (size_t)bt * D_ + h * DH_;
    float acc = 0.f;
#pragma unroll 8
    for (int dh = 0; dh < DH_; ++dh)
        acc += __bfloat162float(qrow[dh]) * omega[dh * F_ + f];
    acc = fmaxf(acc, 0.f);
    if (masked) {
        int b = bt / T_, t = bt % T_;
        if (t >= lengths[b]) acc = 0.f;
    }
    out[o] = acc;
}

// ---------------- Ksum[b,h,f] = sum_s Kf[b,s,h,f] ----------------
__global__ void ksum_kernel(const float* __restrict__ Kf, float* __restrict__ Ksum) {
    int o = blockIdx.x * 256 + threadIdx.x;   // (b,h,f)
    if (o >= B_ * H_ * F_) return;
    int f = o & (F_ - 1);
    int h = (o >> 5) % H_;
    int b = o / (H_ * F_);
    float s = 0.f;
    for (int t = 0; t < T_; ++t)
        s += Kf[((size_t)(b * T_ + t) * H_ + h) * F_ + f];
    Ksum[o] = s;
}

// ---------------- KV[b,h,f,m] = sum_s Kf[b,s,h,f] * v[b,s,h*64+m] ----------------
__global__ void kv_kernel(const float* __restrict__ Kf, const bf16* __restrict__ v,
                          float* __restrict__ KV) {
    int o = blockIdx.x * 256 + threadIdx.x;   // (b,h,f,m)
    if (o >= B_ * H_ * F_ * DH_) return;
    int m = o & (DH_ - 1);
    int f = (o >> 6) & (F_ - 1);
    int h = (o >> 11) % H_;
    int b = o / (H_ * F_ * DH_);
    float acc = 0.f;
    for (int s = 0; s < T_; ++s)
        acc += Kf[((size_t)(b * T_ + s) * H_ + h) * F_ + f]
             * __bfloat162float(v[(size_t)(b * T_ + s) * D_ + h * DH_ + m]);
    KV[o] = acc;
}

// ---------------- attn out: out[bt,h*64+m] = Z * sum_f Qf*KV ; Z stored ----------------
__global__ void attn_out_kernel(const float* __restrict__ Qf, const float* __restrict__ KV,
                                const float* __restrict__ Ksum, float* __restrict__ Z,
                                bf16* __restrict__ out) {
    int o = blockIdx.x * 256 + threadIdx.x;   // (bt, h, m)
    if (o >= BT_ * D_) return;
    int m = o & (DH_ - 1);
    int h = (o >> 6) % H_;
    int bt = o / D_;
    int b = bt / T_;
    const float* qf = Qf + ((size_t)bt * H_ + h) * F_;
    const float* ks = Ksum + ((size_t)b * H_ + h) * F_;
    const float* kv = KV + ((size_t)b * H_ + h) * F_ * DH_;
    float zden = 1e-6f, acc = 0.f;
#pragma unroll
    for (int f = 0; f < F_; ++f) {
        float q = qf[f];
        zden += q * ks[f];
        acc += q * kv[f * DH_ + m];
    }
    float z = 1.0f / zden;
    if (m == 0) Z[(size_t)bt * H_ + h] = z;
    out[(size_t)bt * D_ + h * DH_ + m] = __float2bfloat16(acc * z);
}

// ---------------- attn weights (last layer): w[b,h,t,s] = Z[b,t,h]*sum_f Qf[b,t,h,f]*Kf[b,s,h,f] ----------------
__global__ void attnw_kernel(const float* __restrict__ Qf, const float* __restrict__ Kf,
                             const float* __restrict__ Z, float* __restrict__ out) {
    __shared__ float qf[F_];
    int idx = blockIdx.x;          // (b,h,t)
    int t = idx % T_;
    int h = (idx / T_) % H_;
    int b = idx / (T_ * H_);
    int tid = threadIdx.x;
    if (tid < F_) qf[tid] = Qf[((size_t)(b * T_ + t) * H_ + h) * F_ + tid];
    __syncthreads();
    if (tid < T_) {
        float z = Z[(size_t)(b * T_ + t) * H_ + h];
        const float* kf = Kf + ((size_t)(b * T_ + tid) * H_ + h) * F_;
        float acc = 0.f;
#pragma unroll
        for (int f = 0; f < F_; ++f) acc += qf[f] * kf[f];
        out[(size_t)idx * T_ + tid] = acc * z;
    }
}

// ---------------- x = LN(x + res) * g + b ----------------
__global__ __launch_bounds__(256) void ln_kernel(float* __restrict__ x, const bf16* __restrict__ res,
                                                 const float* __restrict__ g, const float* __restrict__ bb) {
    __shared__ float row[D_];
    __shared__ float red[256];
    int bt = blockIdx.x, tid = threadIdx.x;
    float* xr = x + (size_t)bt * D_;
    const bf16* rr = res + (size_t)bt * D_;
    float lsum = 0.f;
    for (int i = tid; i < D_; i += 256) {
        float v = xr[i] + __bfloat162float(rr[i]);
        row[i] = v;
        lsum += v;
    }
    red[tid] = lsum; __syncthreads();
    for (int s2 = 128; s2 > 0; s2 >>= 1) { if (tid < s2) red[tid] += red[tid + s2]; __syncthreads(); }
    float mean = red[0] * (1.0f / D_);
    __syncthreads();
    float lss = 0.f;
    for (int i = tid; i < D_; i += 256) { float d = row[i] - mean; lss += d * d; }
    red[tid] = lss; __syncthreads();
    for (int s2 = 128; s2 > 0; s2 >>= 1) { if (tid < s2) red[tid] += red[tid + s2]; __syncthreads(); }
    float rstd = rsqrtf(red[0] * (1.0f / D_) + 1e-5f);
    for (int i = tid; i < D_; i += 256)
        xr[i] = (row[i] - mean) * rstd * g[i] + bb[i];
}

// ---------------- CLS writeout ----------------
__global__ void cls_kernel(const float* __restrict__ x, float* __restrict__ out) {
    int o = blockIdx.x * 256 + threadIdx.x;
    if (o >= B_ * D_) return;
    int b = o / D_, d = o % D_;
    out[o] = x[(size_t)(b * T_) * D_ + d];
}

extern "C" void kernel_launch(void* const* d_in, const int* in_sizes, int n_in,
                              void* d_out, int out_size, void* d_ws, size_t ws_size,
                              hipStream_t stream) {
    const int*   batch = (const int*)d_in[0];
    const unsigned char* mask = (const unsigned char*)d_in[1];
    const float* tok  = (const float*)d_in[2];
    const float* pos  = (const float*)d_in[3];
    const float* Wq   = (const float*)d_in[4];
    const float* bq   = (const float*)d_in[5];
    const float* Wk   = (const float*)d_in[6];
    const float* bk   = (const float*)d_in[7];
    const float* Wv   = (const float*)d_in[8];
    const float* bv   = (const float*)d_in[9];
    const float* Wo   = (const float*)d_in[10];
    const float* bo   = (const float*)d_in[11];
    const float* omega= (const float*)d_in[12];
    const float* ln1g = (const float*)d_in[13];
    const float* ln1b = (const float*)d_in[14];
    const float* ln2g = (const float*)d_in[15];
    const float* ln2b = (const float*)d_in[16];
    const float* W1   = (const float*)d_in[17];
    const float* b1   = (const float*)d_in[18];
    const float* W2   = (const float*)d_in[19];
    const float* b2   = (const float*)d_in[20];

    float* out_cls  = (float*)d_out;                   // [B, D]
    float* out_attn = (float*)d_out + B_ * D_;         // [B, H, T, T]

    // workspace layout (bytes) — total ~180 MB
    char* wsb = (char*)d_ws;
    float* x   = (float*)wsb; wsb += (size_t)BT_ * D_ * 4;        // 49.2 MB
    bf16* q16  = (bf16*)wsb;  wsb += (size_t)BT_ * D_ * 2;        // 24.6 MB
    bf16* k16  = (bf16*)wsb;  wsb += (size_t)BT_ * D_ * 2;
    bf16* v16  = (bf16*)wsb;  wsb += (size_t)BT_ * D_ * 2;
    float* Qf  = (float*)wsb; wsb += (size_t)BT_ * H_ * F_ * 4;   // 24.6 MB
    float* Kf  = (float*)wsb; wsb += (size_t)BT_ * H_ * F_ * 4;
    float* KV  = (float*)wsb; wsb += (size_t)B_ * H_ * F_ * DH_ * 4;
    float* Ksum= (float*)wsb; wsb += (size_t)B_ * H_ * F_ * 4;
    float* Z   = (float*)wsb; wsb += (size_t)BT_ * H_ * 4;
    int* lengths = (int*)wsb; wsb += B_ * 4;

    lengths_kernel<<<1, 256, 0, stream>>>(mask, lengths);
    embed_kernel<<<BT_, 256, 0, stream>>>(batch, tok, pos, x);

    dim3 gg(D_ / BN, BT_ / BM);   // (12, 250)
    const size_t WSTRIDE = (size_t)D_ * D_;

    for (int l = 0; l < L_; ++l) {
        const float *Wq_l = Wq + l * WSTRIDE, *bq_l = bq + l * D_;
        const float *Wk_l = Wk + l * WSTRIDE, *bk_l = bk + l * D_;
        const float *Wv_l = Wv + l * WSTRIDE, *bv_l = bv + l * D_;
        const float *Wo_l = Wo + l * WSTRIDE, *bo_l = bo + l * D_;
        const float *W1_l = W1 + l * WSTRIDE, *b1_l = b1 + l * D_;
        const float *W2_l = W2 + l * WSTRIDE, *b2_l = b2 + l * D_;
        const float *om_l = omega + (size_t)l * DH_ * F_;

        sgemm_bias<float, bf16><<<gg, 256, 0, stream>>>(x, Wq_l, bq_l, q16, 0);
        sgemm_bias<float, bf16><<<gg, 256, 0, stream>>>(x, Wk_l, bk_l, k16, 0);
        sgemm_bias<float, bf16><<<gg, 256, 0, stream>>>(x, Wv_l, bv_l, v16, 0);

        feat_kernel<<<(BT_ * H_ * F_ + 255) / 256, 256, 0, stream>>>(q16, om_l, Qf, lengths, 0);
        feat_kernel<<<(BT_ * H_ * F_ + 255) / 256, 256, 0, stream>>>(k16, om_l, Kf, lengths, 1);

        ksum_kernel<<<(B_ * H_ * F_ + 255) / 256, 256, 0, stream>>>(Kf, Ksum);
        kv_kernel<<<(B_ * H_ * F_ * DH_ + 255) / 256, 256, 0, stream>>>(Kf, v16, KV);

        attn_out_kernel<<<(BT_ * D_ + 255) / 256, 256, 0, stream>>>(Qf, KV, Ksum, Z, q16);

        if (l == L_ - 1)
            attnw_kernel<<<B_ * H_ * T_, 256, 0, stream>>>(Qf, Kf, Z, out_attn);

        sgemm_bias<bf16, bf16><<<gg, 256, 0, stream>>>(q16, Wo_l, bo_l, k16, 0);
        ln_kernel<<<BT_, 256, 0, stream>>>(x, k16, ln1g + l * D_, ln1b + l * D_);

        sgemm_bias<float, bf16><<<gg, 256, 0, stream>>>(x, W1_l, b1_l, v16, 1);   // + exact GELU
        sgemm_bias<bf16, bf16><<<gg, 256, 0, stream>>>(v16, W2_l, b2_l, k16, 0);
        ln_kernel<<<BT_, 256, 0, stream>>>(x, k16, ln2g + l * D_, ln2b + l * D_);
    }

    cls_kernel<<<(B_ * D_ + 255) / 256, 256, 0, stream>>>(x, out_cls);
}

// Round 3
// 7227.675 us; speedup vs baseline: 4.6410x; 4.6410x over previous
//
#include <hip/hip_runtime.h>
#include <hip/hip_bf16.h>

typedef __hip_bfloat16 bf16;
typedef __attribute__((ext_vector_type(4))) float f32x4;
typedef __attribute__((ext_vector_type(8))) short bf16x8;

#define B_ 64
#define T_ 250
#define D_ 768
#define H_ 12
#define DH_ 64
#define F_ 32
#define L_ 12
#define BT_ (B_*T_)   // 16000
#define NF_ (H_*F_)   // 384

// ---------------- lengths (mask dtype autodetect: int32 / float32 / bool8) ----------------
__global__ void lengths_kernel(const unsigned char* __restrict__ mask, int* __restrict__ lengths) {
    __shared__ int not_i32, not_f32;
    const unsigned int* w = (const unsigned int*)mask;
    int tid = threadIdx.x;
    if (tid == 0) { not_i32 = 0; not_f32 = 0; }
    __syncthreads();
    int li = 0, lf = 0;
    for (int i = tid; i < 4000; i += 256) {
        unsigned int v = w[i];
        if (v > 1u) li = 1;
        if (v != 0u && v != 0x3F800000u) lf = 1;
    }
    if (li) not_i32 = 1;
    if (lf) not_f32 = 1;
    __syncthreads();
    int mode = (!not_i32) ? 0 : ((!not_f32) ? 1 : 2);
    if (tid < B_) {
        int cnt = 0;
        if (mode == 0) {
            const int* r = (const int*)mask + tid * T_;
            for (int t = 0; t < T_; ++t) cnt += (r[t] != 0);
        } else if (mode == 1) {
            const unsigned int* r = w + tid * T_;
            for (int t = 0; t < T_; ++t) cnt += (r[t] != 0);
        } else {
            const unsigned char* r = mask + tid * T_;
            for (int t = 0; t < T_; ++t) cnt += (r[t] != 0);
        }
        lengths[tid] = cnt;
    }
}

// ---------------- embedding: x f32 + xb bf16 shadow ----------------
__global__ void embed_kernel(const int* __restrict__ batch, const float* __restrict__ tok,
                             const float* __restrict__ pos, float* __restrict__ x,
                             bf16* __restrict__ xb) {
    int bt = blockIdx.x;
    int t = bt % T_;
    int tok_id = batch[bt];
    const float* tr = tok + (size_t)tok_id * D_;
    const float* pr = pos + (size_t)t * D_;
    float* xr = x + (size_t)bt * D_;
    bf16* xbr = xb + (size_t)bt * D_;
    for (int d = threadIdx.x; d < D_; d += 256) {
        float v = tr[d] + pr[d];
        xr[d] = v;
        xbr[d] = __float2bfloat16(v);
    }
}

// ---------------- per-layer weight transpose+cast: W f32 [K,N] -> Wt bf16 [N,K] ----------------
__global__ __launch_bounds__(256) void transpose_w(
    const float* __restrict__ Wq, const float* __restrict__ Wk, const float* __restrict__ Wv,
    const float* __restrict__ Wo, const float* __restrict__ W1, const float* __restrict__ W2,
    int l, bf16* __restrict__ Wt)
{
    __shared__ float tile[32][33];
    int m = blockIdx.z;
    const float* src;
    switch (m) {
        case 0: src = Wq; break; case 1: src = Wk; break; case 2: src = Wv; break;
        case 3: src = Wo; break; case 4: src = W1; break; default: src = W2; break;
    }
    src += (size_t)l * D_ * D_;
    bf16* dst = Wt + (size_t)m * D_ * D_;
    int k0 = blockIdx.y * 32, n0 = blockIdx.x * 32;
    int tx = threadIdx.x, ty = threadIdx.y;
#pragma unroll
    for (int i = 0; i < 4; ++i)
        tile[ty + i * 8][tx] = src[(size_t)(k0 + ty + i * 8) * D_ + n0 + tx];
    __syncthreads();
#pragma unroll
    for (int i = 0; i < 4; ++i)
        dst[(size_t)(n0 + ty + i * 8) * D_ + k0 + tx] = __float2bfloat16(tile[tx][ty + i * 8]);
}

// ---------------- block-diagonal omega^T: WomT[n=h*32+f][k] = (k/64==h) ? om[k%64][f] : 0 ----------------
__global__ void build_wom(const float* __restrict__ om, bf16* __restrict__ wt) {
    int o = blockIdx.x * 256 + threadIdx.x;     // n*768 + k
    if (o >= NF_ * D_) return;
    int n = o / D_, k = o - n * D_;
    float v = ((k >> 6) == (n >> 5)) ? om[(k & 63) * F_ + (n & 31)] : 0.f;
    wt[o] = __float2bfloat16(v);
}

// ---------------- MFMA GEMM: C[16000,N] = A[16000,768] @ Bt[N,768]^T + bias, epilogue acts ----------------
// act: 0 = none, 1 = exact GELU, 2 = relu, 3 = relu + prefix-length mask (rows are bt)
__global__ __launch_bounds__(256) void gemm_bt(
    const bf16* __restrict__ A, const bf16* __restrict__ Bt,
    const float* __restrict__ bias, bf16* __restrict__ C,
    int N, int act, const int* __restrict__ lengths)
{
    const int K = D_;
    __shared__ __attribute__((aligned(16))) short As[128 * 32];
    __shared__ __attribute__((aligned(16))) short Bs[128 * 32];
    const int tid = threadIdx.x;
    const int lane = tid & 63, wave = tid >> 6;
    const int row0 = blockIdx.y * 128, col0 = blockIdx.x * 128;
    const int wm = (wave >> 1) * 64, wn = (wave & 1) * 64;

    f32x4 acc[4][4];
#pragma unroll
    for (int i = 0; i < 4; ++i)
#pragma unroll
        for (int j = 0; j < 4; ++j) acc[i][j] = (f32x4){0.f, 0.f, 0.f, 0.f};

    const int srow = lane >> 2;            // 0..15
    const int scol = (lane & 3) * 8;       // element offset within 32
    const short* Ag = (const short*)A + (size_t)(row0 + srow) * K + scol;
    const short* Bg = (const short*)Bt + (size_t)(col0 + srow) * K + scol;

    for (int k0 = 0; k0 < K; k0 += 32) {
#pragma unroll
        for (int c = 0; c < 2; ++c) {
            int cc = wave * 2 + c;
            __builtin_amdgcn_global_load_lds(
                (const __attribute__((address_space(1))) unsigned int*)(Ag + (size_t)cc * 16 * K + k0),
                (__attribute__((address_space(3))) unsigned int*)(As + cc * 512), 16, 0, 0);
            __builtin_amdgcn_global_load_lds(
                (const __attribute__((address_space(1))) unsigned int*)(Bg + (size_t)cc * 16 * K + k0),
                (__attribute__((address_space(3))) unsigned int*)(Bs + cc * 512), 16, 0, 0);
        }
        __syncthreads();
        bf16x8 af[4], bfr[4];
#pragma unroll
        for (int mi = 0; mi < 4; ++mi)
            af[mi] = *(const bf16x8*)(As + ((wm + mi * 16 + (lane & 15)) << 5) + ((lane >> 4) << 3));
#pragma unroll
        for (int ni = 0; ni < 4; ++ni)
            bfr[ni] = *(const bf16x8*)(Bs + ((wn + ni * 16 + (lane & 15)) << 5) + ((lane >> 4) << 3));
#pragma unroll
        for (int mi = 0; mi < 4; ++mi)
#pragma unroll
            for (int ni = 0; ni < 4; ++ni)
                acc[mi][ni] = __builtin_amdgcn_mfma_f32_16x16x32_bf16(af[mi], bfr[ni], acc[mi][ni], 0, 0, 0);
        __syncthreads();
    }

    float bj[4];
#pragma unroll
    for (int ni = 0; ni < 4; ++ni) {
        int col = col0 + wn + ni * 16 + (lane & 15);
        bj[ni] = bias ? bias[col] : 0.f;
    }
#pragma unroll
    for (int mi = 0; mi < 4; ++mi) {
#pragma unroll
        for (int r = 0; r < 4; ++r) {
            int row = row0 + wm + mi * 16 + ((lane >> 4) << 2) + r;
            bool kill = false;
            if (act == 3) { int b = row / T_; int t = row - b * T_; kill = (t >= lengths[b]); }
            size_t base = (size_t)row * N + col0 + wn + (lane & 15);
#pragma unroll
            for (int ni = 0; ni < 4; ++ni) {
                float v = acc[mi][ni][r] + bj[ni];
                if (act == 1) v = 0.5f * v * (1.0f + erff(v * 0.70710678118654752f));
                else if (act >= 2) v = fmaxf(v, 0.f);
                if (kill) v = 0.f;
                C[base + ni * 16] = __float2bfloat16(v);
            }
        }
    }
}

// ---------------- Ksum[b,h,f] = sum_s Kf[b,s,h,f] ----------------
__global__ void ksum_kernel(const bf16* __restrict__ Kf, float* __restrict__ Ksum) {
    int o = blockIdx.x * 256 + threadIdx.x;   // (b,h,f)
    if (o >= B_ * H_ * F_) return;
    int f = o & (F_ - 1);
    int h = (o >> 5) % H_;
    int b = o / (H_ * F_);
    float s = 0.f;
    for (int t = 0; t < T_; ++t)
        s += __bfloat162float(Kf[((size_t)(b * T_ + t) * H_ + h) * F_ + f]);
    Ksum[o] = s;
}

// ---------------- KV[b,h,f,m] = sum_s Kf[b,s,h,f] * v[b,s,h*64+m] ----------------
__global__ void kv_kernel(const bf16* __restrict__ Kf, const bf16* __restrict__ v,
                          float* __restrict__ KV) {
    int o = blockIdx.x * 256 + threadIdx.x;   // (b,h,f,m)
    if (o >= B_ * H_ * F_ * DH_) return;
    int m = o & (DH_ - 1);
    int f = (o >> 6) & (F_ - 1);
    int h = (o >> 11) % H_;
    int b = o / (H_ * F_ * DH_);
    float acc = 0.f;
    for (int s = 0; s < T_; ++s)
        acc += __bfloat162float(Kf[((size_t)(b * T_ + s) * H_ + h) * F_ + f])
             * __bfloat162float(v[(size_t)(b * T_ + s) * D_ + h * DH_ + m]);
    KV[o] = acc;
}

// ---------------- attn out: out[bt,h*64+m] = Z * sum_f Qf*KV ; Z stored ----------------
__global__ void attn_out_kernel(const bf16* __restrict__ Qf, const float* __restrict__ KV,
                                const float* __restrict__ Ksum, float* __restrict__ Z,
                                bf16* __restrict__ out) {
    int o = blockIdx.x * 256 + threadIdx.x;   // (bt, h, m)
    if (o >= BT_ * D_) return;
    int m = o & (DH_ - 1);
    int h = (o >> 6) % H_;
    int bt = o / D_;
    int b = bt / T_;
    const bf16* qf = Qf + ((size_t)bt * H_ + h) * F_;
    const float* ks = Ksum + ((size_t)b * H_ + h) * F_;
    const float* kv = KV + ((size_t)b * H_ + h) * F_ * DH_;
    float zden = 1e-6f, acc = 0.f;
#pragma unroll
    for (int f = 0; f < F_; ++f) {
        float q = __bfloat162float(qf[f]);
        zden += q * ks[f];
        acc += q * kv[f * DH_ + m];
    }
    float z = 1.0f / zden;
    if (m == 0) Z[(size_t)bt * H_ + h] = z;
    out[(size_t)bt * D_ + h * DH_ + m] = __float2bfloat16(acc * z);
}

// ---------------- attn weights (tiled): w[b,h,t,s] = Z[b,t,h]*sum_f Qf[b,t,h,f]*Kf[b,s,h,f] ----------------
__global__ __launch_bounds__(256) void attnw_kernel(const bf16* __restrict__ Qf,
                                                    const bf16* __restrict__ Kf,
                                                    const float* __restrict__ Z,
                                                    float* __restrict__ out) {
    __shared__ float Qs[64][33];
    __shared__ float Ks[64][33];
    __shared__ float Zs[64];
    int tt = blockIdx.x;            // t-tile 0..3
    int bh = blockIdx.y;            // b*H+h
    int b = bh / H_, h = bh - b * H_;
    int tid = threadIdx.x;
    int t0 = tt * 64;
    int rr = tid >> 2, f0 = (tid & 3) * 8;
    {
        int t = t0 + rr;
        bool ok = (t < T_);
        const bf16* src = Qf + ((size_t)(b * T_ + (ok ? t : 0)) * H_ + h) * F_ + f0;
#pragma unroll
        for (int j = 0; j < 8; ++j) Qs[rr][f0 + j] = ok ? __bfloat162float(src[j]) : 0.f;
        if (tid < 64) {
            int tz = t0 + tid;
            Zs[tid] = (tz < T_) ? Z[(size_t)(b * T_ + tz) * H_ + h] : 0.f;
        }
    }
    int tx = tid & 15, ty = tid >> 4;
    for (int s0 = 0; s0 < T_; s0 += 64) {
        __syncthreads();
        {
            int s = s0 + rr;
            bool ok = (s < T_);
            const bf16* src = Kf + ((size_t)(b * T_ + (ok ? s : 0)) * H_ + h) * F_ + f0;
#pragma unroll
            for (int j = 0; j < 8; ++j) Ks[rr][f0 + j] = ok ? __bfloat162float(src[j]) : 0.f;
        }
        __syncthreads();
        float accw[4][4] = {};
#pragma unroll
        for (int f = 0; f < F_; ++f) {
            float qv[4], kv4[4];
#pragma unroll
            for (int i = 0; i < 4; ++i) qv[i] = Qs[ty * 4 + i][f];
#pragma unroll
            for (int j = 0; j < 4; ++j) kv4[j] = Ks[tx * 4 + j][f];
#pragma unroll
            for (int i = 0; i < 4; ++i)
#pragma unroll
                for (int j = 0; j < 4; ++j) accw[i][j] += qv[i] * kv4[j];
        }
#pragma unroll
        for (int i = 0; i < 4; ++i) {
            int t = t0 + ty * 4 + i;
            if (t >= T_) continue;
            float z = Zs[ty * 4 + i];
            size_t base = ((size_t)bh * T_ + t) * T_ + s0;
#pragma unroll
            for (int j = 0; j < 4; ++j) {
                int s = s0 + tx * 4 + j;
                if (s < T_) out[base + tx * 4 + j] = accw[i][j] * z;
            }
        }
    }
}

// ---------------- x = LN(x + res); writes f32 x and bf16 xb ----------------
__global__ __launch_bounds__(256) void ln_kernel(float* __restrict__ x, const bf16* __restrict__ res,
                                                 const float* __restrict__ g, const float* __restrict__ bb,
                                                 bf16* __restrict__ xb) {
    int bt = blockIdx.x, tid = threadIdx.x;
    float* xr = x + (size_t)bt * D_;
    const bf16* rr = res + (size_t)bt * D_;
    float v[3]; float s = 0.f, ss = 0.f;
#pragma unroll
    for (int i = 0; i < 3; ++i) {
        int idx = tid + i * 256;
        float t = xr[idx] + __bfloat162float(rr[idx]);
        v[i] = t; s += t; ss += t * t;
    }
#pragma unroll
    for (int o = 1; o < 64; o <<= 1) { s += __shfl_xor(s, o, 64); ss += __shfl_xor(ss, o, 64); }
    __shared__ float red[4][2];
    int wave = tid >> 6, lane = tid & 63;
    if (lane == 0) { red[wave][0] = s; red[wave][1] = ss; }
    __syncthreads();
    s = red[0][0] + red[1][0] + red[2][0] + red[3][0];
    ss = red[0][1] + red[1][1] + red[2][1] + red[3][1];
    float mean = s * (1.f / D_);
    float var = ss * (1.f / D_) - mean * mean;
    float rstd = rsqrtf(var + 1e-5f);
    bf16* xbr = xb + (size_t)bt * D_;
#pragma unroll
    for (int i = 0; i < 3; ++i) {
        int idx = tid + i * 256;
        float o = (v[i] - mean) * rstd * g[idx] + bb[idx];
        xr[idx] = o;
        xbr[idx] = __float2bfloat16(o);
    }
}

// ---------------- CLS writeout ----------------
__global__ void cls_kernel(const float* __restrict__ x, float* __restrict__ out) {
    int o = blockIdx.x * 256 + threadIdx.x;
    if (o >= B_ * D_) return;
    int b = o / D_, d = o % D_;
    out[o] = x[(size_t)(b * T_) * D_ + d];
}

extern "C" void kernel_launch(void* const* d_in, const int* in_sizes, int n_in,
                              void* d_out, int out_size, void* d_ws, size_t ws_size,
                              hipStream_t stream) {
    const int*   batch = (const int*)d_in[0];
    const unsigned char* mask = (const unsigned char*)d_in[1];
    const float* tok  = (const float*)d_in[2];
    const float* pos  = (const float*)d_in[3];
    const float* Wq   = (const float*)d_in[4];
    const float* bq   = (const float*)d_in[5];
    const float* Wk   = (const float*)d_in[6];
    const float* bk   = (const float*)d_in[7];
    const float* Wv   = (const float*)d_in[8];
    const float* bv   = (const float*)d_in[9];
    const float* Wo   = (const float*)d_in[10];
    const float* bo   = (const float*)d_in[11];
    const float* omega= (const float*)d_in[12];
    const float* ln1g = (const float*)d_in[13];
    const float* ln1b = (const float*)d_in[14];
    const float* ln2g = (const float*)d_in[15];
    const float* ln2b = (const float*)d_in[16];
    const float* W1   = (const float*)d_in[17];
    const float* b1   = (const float*)d_in[18];
    const float* W2   = (const float*)d_in[19];
    const float* b2   = (const float*)d_in[20];

    float* out_cls  = (float*)d_out;                   // [B, D]
    float* out_attn = (float*)d_out + B_ * D_;         // [B, H, T, T]

    // workspace layout (~187 MB)
    char* wsb = (char*)d_ws;
    float* x   = (float*)wsb; wsb += (size_t)BT_ * D_ * 4;        // 49.2 MB
    bf16* xb   = (bf16*)wsb;  wsb += (size_t)BT_ * D_ * 2;        // 24.6 MB
    bf16* q16  = (bf16*)wsb;  wsb += (size_t)BT_ * D_ * 2;
    bf16* k16  = (bf16*)wsb;  wsb += (size_t)BT_ * D_ * 2;
    bf16* v16  = (bf16*)wsb;  wsb += (size_t)BT_ * D_ * 2;
    bf16* Qf   = (bf16*)wsb;  wsb += (size_t)BT_ * NF_ * 2;       // 12.3 MB
    bf16* Kf   = (bf16*)wsb;  wsb += (size_t)BT_ * NF_ * 2;
    float* KV  = (float*)wsb; wsb += (size_t)B_ * H_ * F_ * DH_ * 4;
    float* Ksum= (float*)wsb; wsb += (size_t)B_ * H_ * F_ * 4;
    float* Z   = (float*)wsb; wsb += (size_t)BT_ * H_ * 4;
    bf16* Wt   = (bf16*)wsb;  wsb += (size_t)6 * D_ * D_ * 2;     // 7.1 MB, reused per layer
    bf16* WomT = (bf16*)wsb;  wsb += (size_t)NF_ * D_ * 2;        // 0.6 MB
    int* lengths = (int*)wsb; wsb += 256;

    lengths_kernel<<<1, 256, 0, stream>>>(mask, lengths);
    embed_kernel<<<BT_, 256, 0, stream>>>(batch, tok, pos, x, xb);

    dim3 gemm_g(D_ / 128, BT_ / 128);     // (6, 125)
    dim3 feat_g(NF_ / 128, BT_ / 128);    // (3, 125)
    dim3 tr_g(24, 24, 6);
    dim3 tr_b(32, 8);
    const size_t WS = (size_t)D_ * D_;

    for (int l = 0; l < L_; ++l) {
        transpose_w<<<tr_g, tr_b, 0, stream>>>(Wq, Wk, Wv, Wo, W1, W2, l, Wt);
        build_wom<<<(NF_ * D_ + 255) / 256, 256, 0, stream>>>(omega + (size_t)l * DH_ * F_, WomT);

        gemm_bt<<<gemm_g, 256, 0, stream>>>(xb, Wt + 0 * WS, bq + l * D_, q16, D_, 0, lengths);
        gemm_bt<<<gemm_g, 256, 0, stream>>>(xb, Wt + 1 * WS, bk + l * D_, k16, D_, 0, lengths);
        gemm_bt<<<gemm_g, 256, 0, stream>>>(xb, Wt + 2 * WS, bv + l * D_, v16, D_, 0, lengths);

        gemm_bt<<<feat_g, 256, 0, stream>>>(q16, WomT, nullptr, Qf, NF_, 2, lengths);   // relu
        gemm_bt<<<feat_g, 256, 0, stream>>>(k16, WomT, nullptr, Kf, NF_, 3, lengths);   // relu+mask

        ksum_kernel<<<(B_ * H_ * F_ + 255) / 256, 256, 0, stream>>>(Kf, Ksum);
        kv_kernel<<<(B_ * H_ * F_ * DH_ + 255) / 256, 256, 0, stream>>>(Kf, v16, KV);
        attn_out_kernel<<<(BT_ * D_ + 255) / 256, 256, 0, stream>>>(Qf, KV, Ksum, Z, q16);

        if (l == L_ - 1)
            attnw_kernel<<<dim3(4, B_ * H_), 256, 0, stream>>>(Qf, Kf, Z, out_attn);

        gemm_bt<<<gemm_g, 256, 0, stream>>>(q16, Wt + 3 * WS, bo + l * D_, k16, D_, 0, lengths);
        ln_kernel<<<BT_, 256, 0, stream>>>(x, k16, ln1g + l * D_, ln1b + l * D_, xb);

        gemm_bt<<<gemm_g, 256, 0, stream>>>(xb, Wt + 4 * WS, b1 + l * D_, v16, D_, 1, lengths); // GELU
        gemm_bt<<<gemm_g, 256, 0, stream>>>(v16, Wt + 5 * WS, b2 + l * D_, k16, D_, 0, lengths);
        ln_kernel<<<BT_, 256, 0, stream>>>(x, k16, ln2g + l * D_, ln2b + l * D_, xb);
    }

    cls_kernel<<<(B_ * D_ + 255) / 256, 256, 0, stream>>>(x, out_cls);
}